// Round 1
// baseline (102.364 us; speedup 1.0000x reference)
//
#include <hip/hip_runtime.h>

#define TPB 128
#define FSTRIDE 108   // floats/residue in LDS: 9 frames x 12 floats; 108 % 32 == 12 -> conflict-free b128 pattern
#define NFRM 9
#define NATOMS 27

// ---------- small matrix helpers (all row-major) ----------

__device__ __forceinline__ void load16(float* M, const float* __restrict__ p) {
    const float4* q = reinterpret_cast<const float4*>(p);
    float4 v0 = q[0], v1 = q[1], v2 = q[2], v3 = q[3];
    M[0]=v0.x; M[1]=v0.y; M[2]=v0.z; M[3]=v0.w;
    M[4]=v1.x; M[5]=v1.y; M[6]=v1.z; M[7]=v1.w;
    M[8]=v2.x; M[9]=v2.y; M[10]=v2.z; M[11]=v2.w;
    M[12]=v3.x; M[13]=v3.y; M[14]=v3.z; M[15]=v3.w;
}

__device__ __forceinline__ void store16(float* __restrict__ p, const float* M) {
    float4* q = reinterpret_cast<float4*>(p);
    q[0] = make_float4(M[0],M[1],M[2],M[3]);
    q[1] = make_float4(M[4],M[5],M[6],M[7]);
    q[2] = make_float4(M[8],M[9],M[10],M[11]);
    q[3] = make_float4(M[12],M[13],M[14],M[15]);
}

__device__ __forceinline__ void stage12(float* sF, int tid, int f, const float* M) {
    float4* d = reinterpret_cast<float4*>(sF + tid*FSTRIDE + f*12);
    d[0] = make_float4(M[0],M[1],M[2],M[3]);
    d[1] = make_float4(M[4],M[5],M[6],M[7]);
    d[2] = make_float4(M[8],M[9],M[10],M[11]);
}

// P(4x4) = [Ar | 0001] * B(4x4); Ar = rows 0..2 incl translation (12 floats)
__device__ __forceinline__ void mul_affine(float* __restrict__ P,
                                           const float* __restrict__ Ar,
                                           const float* __restrict__ B) {
#pragma unroll
    for (int i = 0; i < 3; ++i) {
#pragma unroll
        for (int j = 0; j < 4; ++j) {
            float t = Ar[i*4+0] * B[0*4+j];
            t = fmaf(Ar[i*4+1], B[1*4+j], t);
            t = fmaf(Ar[i*4+2], B[2*4+j], t);
            t = fmaf(Ar[i*4+3], B[3*4+j], t);
            P[i*4+j] = t;
        }
    }
#pragma unroll
    for (int j = 0; j < 4; ++j) P[12+j] = B[12+j];
}

__device__ __forceinline__ void mul_full(float* __restrict__ P,
                                         const float* __restrict__ A,
                                         const float* __restrict__ B) {
#pragma unroll
    for (int i = 0; i < 4; ++i) {
#pragma unroll
        for (int j = 0; j < 4; ++j) {
            float t = A[i*4+0] * B[0*4+j];
            t = fmaf(A[i*4+1], B[1*4+j], t);
            t = fmaf(A[i*4+2], B[2*4+j], t);
            t = fmaf(A[i*4+3], B[3*4+j], t);
            P[i*4+j] = t;
        }
    }
}

// M = M @ rotX(c,s): only columns 1,2 change
__device__ __forceinline__ void apply_rotX(float* M, float c, float s) {
#pragma unroll
    for (int i = 0; i < 4; ++i) {
        float t1 = M[i*4+1], t2 = M[i*4+2];
        M[i*4+1] = fmaf(t2, s, t1*c);        //  c*t1 + s*t2
        M[i*4+2] = fmaf(t2, c, -(t1*s));     // -s*t1 + c*t2
    }
}

// M = M @ rotZ(c,s): only columns 0,1 change
__device__ __forceinline__ void apply_rotZ(float* M, float c, float s) {
#pragma unroll
    for (int i = 0; i < 4; ++i) {
        float t0 = M[i*4+0], t1 = M[i*4+1];
        M[i*4+0] = fmaf(t1, s, t0*c);
        M[i*4+1] = fmaf(t1, c, -(t0*s));
    }
}

__device__ __forceinline__ void rot_axis3(float* R, float ct, float st,
                                          float u0, float u1, float u2) {
    float omc = 1.0f - ct;
    R[0] = ct + u0*u0*omc;       R[1] = u0*u1*omc - u2*st;   R[2] = u0*u2*omc + u1*st;
    R[3] = u0*u1*omc + u2*st;    R[4] = ct + u1*u1*omc;      R[5] = u1*u2*omc - u0*st;
    R[6] = u0*u2*omc - u1*st;    R[7] = u1*u2*omc + u0*st;   R[8] = ct + u2*u2*omc;
}

// C(3x3) = A(rows stride 4, cols 0..2) @ B(3x3)
__device__ __forceinline__ void mul3_a4(float* C, const float* A, const float* B) {
#pragma unroll
    for (int i = 0; i < 3; ++i)
#pragma unroll
        for (int j = 0; j < 3; ++j) {
            float t = A[i*4+0] * B[0*3+j];
            t = fmaf(A[i*4+1], B[1*3+j], t);
            t = fmaf(A[i*4+2], B[2*3+j], t);
            C[i*3+j] = t;
        }
}

__device__ __forceinline__ void mul3(float* C, const float* A, const float* B) {
#pragma unroll
    for (int i = 0; i < 3; ++i)
#pragma unroll
        for (int j = 0; j < 3; ++j) {
            float t = A[i*3+0] * B[0*3+j];
            t = fmaf(A[i*3+1], B[1*3+j], t);
            t = fmaf(A[i*3+2], B[2*3+j], t);
            C[i*3+j] = t;
        }
}

// ---------- kernel ----------

extern "C" __global__ void __launch_bounds__(TPB, 1)
caac_kernel(const float* __restrict__ xyz,     // (L,3,3)
            const float* __restrict__ alphas,  // (L,10,2)
            const float* __restrict__ RTs,     // (22,7,4,4)
            const float* __restrict__ bxyz,    // (22,27,4)
            const int*   __restrict__ seq,     // (L)
            const int*   __restrict__ bidx,    // (22,27)
            float* __restrict__ outF,          // (L,9,4,4)
            float* __restrict__ outX,          // (L,27,3)
            int L)
{
    __shared__ float sF[TPB * FSTRIDE];
    __shared__ int   sSeq[TPB];

    const int tid = threadIdx.x;
    const int l   = blockIdx.x * TPB + tid;

    if (l < L) {
        // ---- rigid_from_3_points(N=xyz[l,0], Ca=xyz[l,1], C=xyz[l,2]) ----
        const float* xp = xyz + (size_t)l * 9;
        float Nx=xp[0], Ny=xp[1], Nz=xp[2];
        float Ax=xp[3], Ay=xp[4], Az=xp[5];
        float Cx=xp[6], Cy=xp[7], Cz=xp[8];

        float v1x=Cx-Ax, v1y=Cy-Ay, v1z=Cz-Az;
        float v2x=Nx-Ax, v2y=Ny-Ay, v2z=Nz-Az;
        float n1 = sqrtf(v1x*v1x + v1y*v1y + v1z*v1z) + 1e-8f;
        float e1x=v1x/n1, e1y=v1y/n1, e1z=v1z/n1;
        float dp = e1x*v2x + e1y*v2y + e1z*v2z;
        float u2x = v2x - dp*e1x, u2y = v2y - dp*e1y, u2z = v2z - dp*e1z;
        float n2 = sqrtf(u2x*u2x + u2y*u2y + u2z*u2z) + 1e-8f;
        float e2x=u2x/n2, e2y=u2y/n2, e2z=u2z/n2;
        float e3x = e1y*e2z - e1z*e2y;
        float e3y = e1z*e2x - e1x*e2z;
        float e3z = e1x*e2y - e1y*e2x;

        // RTF0 rows 0..2 = [e1 e2 e3 | Ca] (R columns are e1,e2,e3)
        float M0[12] = { e1x, e2x, e3x, Ax,
                         e1y, e2y, e3y, Ay,
                         e1z, e2z, e3z, Az };

        int s = seq[l];
        sSeq[tid] = s;

        // ---- alphas -> (cos, sin) for all 10 angles ----
        float ca[10], sa[10];
        const float* ap = alphas + (size_t)l * 20;
#pragma unroll
        for (int k = 0; k < 10; ++k) {
            float a0 = ap[2*k], a1 = ap[2*k+1];
            float n = sqrtf(a0*a0 + a1*a1) + 1e-6f;
            ca[k] = a0 / n;
            sa[k] = a1 / n;
        }

        float* ofr = outF + (size_t)l * 144;

        // ---- frame 0 ----
        {
            float F[16];
#pragma unroll
            for (int k = 0; k < 12; ++k) F[k] = M0[k];
            F[12]=0.f; F[13]=0.f; F[14]=0.f; F[15]=1.f;
            store16(ofr, F);
            stage12(sF, tid, 0, F);
        }

        const float* rtbase = RTs + (size_t)s * 112;  // 7*16 floats

        // ---- frames 1..3: (RTF0 @ RTk) @ rotX(alpha_k) ----
#pragma unroll
        for (int k = 0; k < 3; ++k) {
            float Bm[16]; load16(Bm, rtbase + k*16);
            float P[16];
            mul_affine(P, M0, Bm);
            apply_rotX(P, ca[k], sa[k]);
            store16(ofr + (k+1)*16, P);
            stage12(sF, tid, k+1, P);
        }

        // ---- RTF8 = (RTF0 @ CBrot1) @ CBrot2  (all affine, T unchanged) ----
        const float* bx = bxyz + (size_t)s * 108;  // 27*4 floats
        float4 b0 = ((const float4*)bx)[0];
        float4 b1 = ((const float4*)bx)[1];
        float4 b2 = ((const float4*)bx)[2];
        float4 b4 = ((const float4*)bx)[4];
        float NCrx = 0.5f*(b2.x+b0.x), NCry = 0.5f*(b2.y+b0.y), NCrz = 0.5f*(b2.z+b0.z);
        float CBAx = b4.x-b1.x, CBAy = b4.y-b1.y, CBAz = b4.z-b1.z;   // CBr - CAr
        float NCAx = NCrx-b1.x, NCAy = NCry-b1.y, NCAz = NCrz-b1.z;   // NCr - CAr
        float a1x = CBAy*NCAz - CBAz*NCAy;
        float a1y = CBAz*NCAx - CBAx*NCAz;
        float a1z = CBAx*NCAy - CBAy*NCAx;
        float a1n = sqrtf(a1x*a1x + a1y*a1y + a1z*a1z) + 1e-8f;
        a1x/=a1n; a1y/=a1n; a1z/=a1n;
        float NCpx = b2.x-b0.x, NCpy = b2.y-b0.y, NCpz = b2.z-b0.z;
        float num = NCpx*NCrx + NCpy*NCry + NCpz*NCrz;
        float den = NCrx*NCrx + NCry*NCry + NCrz*NCrz;
        float tq  = num / den;
        float NCppx = NCpx - tq*NCrx, NCppy = NCpy - tq*NCry, NCppz = NCpz - tq*NCrz;
        float a2x = CBAy*NCppz - CBAz*NCppy;
        float a2y = CBAz*NCppx - CBAx*NCppz;
        float a2z = CBAx*NCppy - CBAy*NCppx;
        float a2n = sqrtf(a2x*a2x + a2y*a2y + a2z*a2z) + 1e-8f;
        a2x/=a2n; a2y/=a2n; a2z/=a2n;

        float C1[9], C2[9], E[9], Fr[9];
        rot_axis3(C1, ca[7], sa[7], a1x, a1y, a1z);
        rot_axis3(C2, ca[8], sa[8], a2x, a2y, a2z);
        mul3_a4(E, M0, C1);
        mul3(Fr, E, C2);

        float M8[12] = { Fr[0],Fr[1],Fr[2],M0[3],
                         Fr[3],Fr[4],Fr[5],M0[7],
                         Fr[6],Fr[7],Fr[8],M0[11] };
        {
            float F[16];
#pragma unroll
            for (int k = 0; k < 12; ++k) F[k] = M8[k];
            F[12]=0.f; F[13]=0.f; F[14]=0.f; F[15]=1.f;
            store16(ofr + 8*16, F);
            stage12(sF, tid, 8, F);
        }

        // ---- RTF4 = ((RTF8 @ RT3) @ rotX(a3)) @ rotZ(a9) ----
        float P[16];
        {
            float Bm[16]; load16(Bm, rtbase + 3*16);
            mul_affine(P, M8, Bm);
            apply_rotX(P, ca[3], sa[3]);
            apply_rotZ(P, ca[9], sa[9]);
            store16(ofr + 4*16, P);
            stage12(sF, tid, 4, P);
        }

        // ---- RTF5..7: chain of full 4x4 @ RTk then rotX ----
#pragma unroll
        for (int k = 4; k < 7; ++k) {
            float Bm[16]; load16(Bm, rtbase + k*16);
            float Q[16];
            mul_full(Q, P, Bm);
            apply_rotX(Q, ca[k], sa[k]);
            store16(ofr + (k+1)*16, Q);
            stage12(sF, tid, k+1, Q);
#pragma unroll
            for (int z = 0; z < 16; ++z) P[z] = Q[z];
        }
    }

    __syncthreads();

    // ---- atom phase: block-cooperative, fully coalesced xyz writes ----
    const int bb_res = blockIdx.x * TPB;
    int nres = L - bb_res; if (nres > TPB) nres = TPB;
    const unsigned total = (unsigned)nres * 81u;
    float* ox = outX + (size_t)bb_res * 81;
    for (unsigned i = tid; i < total; i += TPB) {
        unsigned r = i / 81u;
        unsigned c = i - r*81u;
        unsigned a = c / 3u;
        unsigned d = c - a*3u;
        int s2 = sSeq[r];
        int ii = s2*27 + (int)a;
        int idx = bidx[ii];
        float4 bv = ((const float4*)bxyz)[ii];
        const float4 fr = *((const float4*)(sF + r*FSTRIDE + idx*12 + d*4));
        float val = fr.x * bv.x;
        val = fmaf(fr.y, bv.y, val);
        val = fmaf(fr.z, bv.z, val);
        val = fmaf(fr.w, bv.w, val);
        ox[i] = val;
    }
}

extern "C" void kernel_launch(void* const* d_in, const int* in_sizes, int n_in,
                              void* d_out, int out_size, void* d_ws, size_t ws_size,
                              hipStream_t stream) {
    const float* xyz    = (const float*)d_in[0];
    const float* alphas = (const float*)d_in[1];
    const float* RTs    = (const float*)d_in[2];
    const float* bxyz   = (const float*)d_in[3];
    const int*   seq    = (const int*)d_in[4];
    const int*   bidx   = (const int*)d_in[5];
    const int L = in_sizes[4];             // seq has L elements
    float* outF = (float*)d_out;
    float* outX = outF + (size_t)L * 144;  // RTframes then xyzs, flat in return order
    const int grid = (L + TPB - 1) / TPB;
    hipLaunchKernelGGL(caac_kernel, dim3(grid), dim3(TPB), 0, stream,
                       xyz, alphas, RTs, bxyz, seq, bidx, outF, outX, L);
}